// Round 2
// baseline (624.741 us; speedup 1.0000x reference)
//
#include <hip/hip_runtime.h>
#include <math.h>

#define N_TOT 8192
#define N_SRC 4096
#define D_DIM 512
#define BM 128
#define BK 32
#define NT (N_TOT / BM)          /* 64 tiles per dim */
#define NTILES (NT * (NT + 1) / 2) /* 2080 triangular tiles */

// ws layout:
//   bytes [0,32)    : double accum[4]  {0=sum sq, 1=||colsum||^2, 2=loss}
//   bytes [256,276) : float invbw[5]
//   bytes [512, +32KB) : float sq[8192]
//   then             : float w[4096]

__global__ __launch_bounds__(256) void k_rowstats(const float* __restrict__ x,
                                                  double* __restrict__ accum,
                                                  float* __restrict__ sq) {
    const int wave = threadIdx.x >> 6;
    const int lane = threadIdx.x & 63;
    const int row = blockIdx.x * 4 + wave;
    const float* xr = x + (size_t)row * D_DIM;
    float s = 0.f;
#pragma unroll
    for (int k = 0; k < D_DIM / 64; ++k) {
        float v = xr[lane + k * 64];
        s = fmaf(v, v, s);
    }
#pragma unroll
    for (int off = 32; off; off >>= 1) s += __shfl_xor(s, off);
    __shared__ float ls[4];
    if (lane == 0) { sq[row] = s; ls[wave] = s; }
    __syncthreads();
    if (threadIdx.x == 0) {
        double t = (double)ls[0] + (double)ls[1] + (double)ls[2] + (double)ls[3];
        atomicAdd(&accum[0], t);
    }
}

__global__ __launch_bounds__(256) void k_colsum(const float* __restrict__ x,
                                                double* __restrict__ accum) {
    const int col = blockIdx.x;
    double s = 0.0;
    for (int r = threadIdx.x; r < N_TOT; r += 256)
        s += (double)x[(size_t)r * D_DIM + col];
    __shared__ double ls[256];
    ls[threadIdx.x] = s;
    __syncthreads();
    for (int off = 128; off; off >>= 1) {
        if (threadIdx.x < off) ls[threadIdx.x] += ls[threadIdx.x + off];
        __syncthreads();
    }
    if (threadIdx.x == 0) {
        double sj = ls[0];
        atomicAdd(&accum[1], sj * sj);
    }
}

__global__ void k_bw(const double* __restrict__ accum, float* __restrict__ invbw) {
    if (threadIdx.x == 0) {
        // sum of clamped l2 == analytic sum (clamp only trims diagonal fp noise)
        double sum_l2 = 2.0 * (double)N_TOT * accum[0] - 2.0 * accum[1];
        double bw = sum_l2 / ((double)N_TOT * (double)N_TOT - (double)N_TOT);
        bw *= 0.25;  // / KERNEL_MUL^(KERNEL_NUM/2) = / 2^2
        double m = 1.0;
        for (int i = 0; i < 5; ++i) { invbw[i] = (float)(1.0 / (bw * m)); m *= 2.0; }
    }
}

__global__ __launch_bounds__(256) void k_weights(const float* __restrict__ imw,
                                                 const int* __restrict__ y,
                                                 const int* __restrict__ alpha_p,
                                                 float* __restrict__ w) {
    int i = blockIdx.x * 256 + threadIdx.x;
    if (i < N_SRC) {
        float a = (float)alpha_p[0];
        w[i] = a * imw[y[i]] + (1.0f - a);
    }
}

__global__ __launch_bounds__(256) void k_pairs(const float* __restrict__ x,
                                               const float* __restrict__ sq,
                                               const float* __restrict__ w,
                                               const float* __restrict__ invbw,
                                               double* __restrict__ accum) {
    // decode triangular tile index -> (ti, tj), ti <= tj
    int ti = 0, rem = blockIdx.x;
    while (rem >= NT - ti) { rem -= NT - ti; ++ti; }
    const int tj = ti + rem;
    const int i0 = ti * BM, j0 = tj * BM;

    __shared__ float As[BK][BM + 4];
    __shared__ float Bs[BK][BM + 4];

    const int tx = threadIdx.x & 15, ty = threadIdx.x >> 4;
    const int tx8 = tx * 8, ty8 = ty * 8;

    float acc[8][8];
#pragma unroll
    for (int u = 0; u < 8; ++u)
#pragma unroll
        for (int v = 0; v < 8; ++v) acc[u][v] = 0.f;

    for (int kk = 0; kk < D_DIM; kk += BK) {
#pragma unroll
        for (int q = 0; q < 4; ++q) {
            int idx = q * 256 + threadIdx.x;
            int m = idx >> 3;
            int c = (idx & 7) << 2;
            float4 va = *(const float4*)(x + (size_t)(i0 + m) * D_DIM + kk + c);
            As[c + 0][m] = va.x; As[c + 1][m] = va.y;
            As[c + 2][m] = va.z; As[c + 3][m] = va.w;
            float4 vb = *(const float4*)(x + (size_t)(j0 + m) * D_DIM + kk + c);
            Bs[c + 0][m] = vb.x; Bs[c + 1][m] = vb.y;
            Bs[c + 2][m] = vb.z; Bs[c + 3][m] = vb.w;
        }
        __syncthreads();
#pragma unroll
        for (int k = 0; k < BK; ++k) {
            float a[8], bb[8];
            *(float4*)&a[0] = *(const float4*)&As[k][ty8];
            *(float4*)&a[4] = *(const float4*)&As[k][ty8 + 4];
            *(float4*)&bb[0] = *(const float4*)&Bs[k][tx8];
            *(float4*)&bb[4] = *(const float4*)&Bs[k][tx8 + 4];
#pragma unroll
            for (int u = 0; u < 8; ++u)
#pragma unroll
                for (int v = 0; v < 8; ++v)
                    acc[u][v] = fmaf(a[u], bb[v], acc[u][v]);
        }
        __syncthreads();
    }

    // epilogue
    float sqi[8], sqj[8], wiA[8], wjA[8];
#pragma unroll
    for (int u = 0; u < 8; ++u) {
        int i = i0 + ty8 + u;
        sqi[u] = sq[i];
        wiA[u] = (i < N_SRC) ? w[i] : 0.f;
        int j = j0 + tx8 + u;
        sqj[u] = sq[j];
        wjA[u] = (j < N_SRC) ? w[j] : 0.f;
    }
    float ib0 = invbw[0], ib1 = invbw[1], ib2 = invbw[2], ib3 = invbw[3], ib4 = invbw[4];

    const double C_SS = 1.0 / 8386560.0;   // n_s*(n_s-1)/2, same for tt
    const double C_ST = 2.0 / 16777216.0;  // 2 / (n_s*n_t), sign applied below
    const bool diag = (ti == tj);
    const int region = (tj < NT / 2) ? 0 : ((ti >= NT / 2) ? 1 : 2);  // 0=ss 1=tt 2=st

    double lsum = 0.0;
#pragma unroll
    for (int u = 0; u < 8; ++u) {
#pragma unroll
        for (int v = 0; v < 8; ++v) {
            if (diag && (ty8 + u) >= (tx8 + v)) continue;
            float l2 = fmaf(-2.f, acc[u][v], sqi[u] + sqj[v]);
            l2 = fmaxf(l2, 0.f);
            float k5 = expf(-l2 * ib0) + expf(-l2 * ib1) + expf(-l2 * ib2) +
                       expf(-l2 * ib3) + expf(-l2 * ib4);
            float cf;
            if (region == 0)      cf = wiA[u] * wjA[v];
            else if (region == 1) cf = 1.f;
            else                  cf = wiA[u];
            double term = (double)(k5 * cf);
            lsum += (region == 2) ? (-C_ST * term) : (C_SS * term);
        }
    }

    __shared__ double sdl[256];
    sdl[threadIdx.x] = lsum;
    __syncthreads();
    for (int off = 128; off; off >>= 1) {
        if (threadIdx.x < off) sdl[threadIdx.x] += sdl[threadIdx.x + off];
        __syncthreads();
    }
    if (threadIdx.x == 0) atomicAdd(&accum[2], sdl[0]);
}

__global__ void k_out(const double* __restrict__ accum, float* __restrict__ out) {
    if (threadIdx.x == 0) out[0] = (float)accum[2];
}

extern "C" void kernel_launch(void* const* d_in, const int* in_sizes, int n_in,
                              void* d_out, int out_size, void* d_ws, size_t ws_size,
                              hipStream_t stream) {
    const float* x    = (const float*)d_in[0];
    const float* imw  = (const float*)d_in[1];
    const int*   y    = (const int*)d_in[3];
    const int*   alph = (const int*)d_in[4];
    float* out = (float*)d_out;

    char* ws = (char*)d_ws;
    double* accum = (double*)ws;
    float* invbw  = (float*)(ws + 256);
    float* sq     = (float*)(ws + 512);
    float* wgt    = (float*)(ws + 512 + N_TOT * sizeof(float));

    hipMemsetAsync(d_ws, 0, 256, stream);
    k_rowstats<<<N_TOT / 4, 256, 0, stream>>>(x, accum, sq);
    k_colsum<<<D_DIM, 256, 0, stream>>>(x, accum);
    k_bw<<<1, 64, 0, stream>>>(accum, invbw);
    k_weights<<<N_SRC / 256, 256, 0, stream>>>(imw, y, alph, wgt);
    k_pairs<<<NTILES, 256, 0, stream>>>(x, sq, wgt, invbw, accum);
    k_out<<<1, 64, 0, stream>>>(accum, out);
}

// Round 3
// 274.577 us; speedup vs baseline: 2.2753x; 2.2753x over previous
//
#include <hip/hip_runtime.h>
#include <math.h>

#define N_TOT 8192
#define N_SRC 4096
#define D_DIM 512
#define BM 128
#define NT (N_TOT / BM)            /* 64 tiles per dim */
#define NTILES (NT * (NT + 1) / 2) /* 2080 triangular tiles */

typedef short bf16x8 __attribute__((ext_vector_type(8)));
typedef unsigned short u16x8 __attribute__((ext_vector_type(8)));
typedef float f32x4 __attribute__((ext_vector_type(4)));

// ws layout (bytes):
//   0     : double accum[4]   {0=sum of row-sq, 2=loss}
//   64    : float invbw[5]
//   4096  : double colsum[512]
//   8192  : float sq[8192]
//   40960 : float w[4096]
//   65536 : ushort xhi[8192*512]   (8 MB)
//   8454144: ushort xlo[8192*512]  (8 MB)

__device__ __forceinline__ unsigned short f2bf_rn(float v) {
    unsigned int u = __float_as_uint(v);
    unsigned int r = (u + 0x7FFFu + ((u >> 16) & 1u)) >> 16;
    return (unsigned short)r;
}

__global__ __launch_bounds__(256) void k_convert(const float* __restrict__ x,
                                                 unsigned short* __restrict__ xhi,
                                                 unsigned short* __restrict__ xlo) {
    int base = (blockIdx.x * 256 + threadIdx.x) * 8;
    float v[8];
    *(float4*)&v[0] = *(const float4*)(x + base);
    *(float4*)&v[4] = *(const float4*)(x + base + 4);
    u16x8 h, l;
#pragma unroll
    for (int j = 0; j < 8; ++j) {
        unsigned short hb = f2bf_rn(v[j]);
        float hv = __uint_as_float(((unsigned int)hb) << 16);
        h[j] = hb;
        l[j] = f2bf_rn(v[j] - hv);
    }
    *(u16x8*)(xhi + base) = h;
    *(u16x8*)(xlo + base) = l;
}

__global__ __launch_bounds__(256) void k_rowstats(const float* __restrict__ x,
                                                  double* __restrict__ accum,
                                                  float* __restrict__ sq) {
    const int wave = threadIdx.x >> 6;
    const int lane = threadIdx.x & 63;
    const int row = blockIdx.x * 4 + wave;
    const float* xr = x + (size_t)row * D_DIM;
    float s = 0.f;
#pragma unroll
    for (int k = 0; k < D_DIM / 64; ++k) {
        float v = xr[lane + k * 64];
        s = fmaf(v, v, s);
    }
#pragma unroll
    for (int off = 32; off; off >>= 1) s += __shfl_xor(s, off);
    __shared__ float ls[4];
    if (lane == 0) { sq[row] = s; ls[wave] = s; }
    __syncthreads();
    if (threadIdx.x == 0) {
        double t = (double)ls[0] + (double)ls[1] + (double)ls[2] + (double)ls[3];
        atomicAdd(&accum[0], t);
    }
}

// 64 blocks x 128 rows; thread t owns cols {2t, 2t+1}; coalesced row reads.
__global__ __launch_bounds__(256) void k_colsum(const float* __restrict__ x,
                                                double* __restrict__ colsum) {
    const int r0 = blockIdx.x * 128;
    const int c0 = threadIdx.x * 2;
    double s0 = 0.0, s1 = 0.0;
    for (int r = 0; r < 128; ++r) {
        float2 v = *(const float2*)(x + (size_t)(r0 + r) * D_DIM + c0);
        s0 += (double)v.x;
        s1 += (double)v.y;
    }
    atomicAdd(&colsum[c0], s0);
    atomicAdd(&colsum[c0 + 1], s1);
}

__global__ void k_bw(const double* __restrict__ accum,
                     const double* __restrict__ colsum,
                     float* __restrict__ invbw) {
    const int lane = threadIdx.x & 63;
    double s = 0.0;
    for (int c = lane; c < D_DIM; c += 64) {
        double v = colsum[c];
        s += v * v;
    }
#pragma unroll
    for (int off = 32; off; off >>= 1) s += __shfl_xor(s, off);
    if (lane == 0) {
        // sum of clamped l2 == analytic sum (clamp only trims diagonal fp noise)
        double sum_l2 = 2.0 * (double)N_TOT * accum[0] - 2.0 * s;
        double bw = sum_l2 / ((double)N_TOT * (double)N_TOT - (double)N_TOT);
        bw *= 0.25;  // / KERNEL_MUL^(KERNEL_NUM/2)
        double m = 1.0;
        for (int i = 0; i < 5; ++i) { invbw[i] = (float)(1.0 / (bw * m)); m *= 2.0; }
    }
}

__global__ __launch_bounds__(256) void k_weights(const float* __restrict__ imw,
                                                 const int* __restrict__ y,
                                                 const int* __restrict__ alpha_p,
                                                 float* __restrict__ w) {
    int i = blockIdx.x * 256 + threadIdx.x;
    if (i < N_SRC) {
        float a = (float)alpha_p[0];
        w[i] = a * imw[y[i]] + (1.0f - a);
    }
}

__device__ __forceinline__ void gload_lds16(const unsigned short* g, char* l) {
    __builtin_amdgcn_global_load_lds((const __attribute__((address_space(1))) void*)g,
                                     (__attribute__((address_space(3))) void*)l,
                                     16, 0, 0);
}

// swizzle: chunk-of-16B index XOR'd with row bits -> 2-way max bank aliasing
__device__ __forceinline__ int swz_of(int row) { return (row & 3) ^ ((row >> 2) & 3); }

__global__ __launch_bounds__(256) void k_pairs(const unsigned short* __restrict__ xhi,
                                               const unsigned short* __restrict__ xlo,
                                               const float* __restrict__ sq,
                                               const float* __restrict__ w,
                                               const float* __restrict__ invbw,
                                               double* __restrict__ accum) {
    // triangular tile decode: (ti, tj), ti <= tj
    int ti = 0, rem = blockIdx.x;
    while (rem >= NT - ti) { rem -= NT - ti; ++ti; }
    const int tj = ti + rem;
    const int i0 = ti * BM, j0 = tj * BM;

    // 4 swizzled tiles [128 rows][32 bf16] = 8 KB each: hiA, loA, hiB, loB
    __shared__ __align__(16) char lds[4 * 8192];
    char* lAh = lds;
    char* lAl = lds + 8192;
    char* lBh = lds + 16384;
    char* lBl = lds + 24576;

    const int tid = threadIdx.x;
    const int lane = tid & 63;
    const int wave = tid >> 6;
    const int wr = wave >> 1, wc = wave & 1;   // 2x2 wave quadrants, 64x64 each
    const int lr = lane & 15, lg = lane >> 4;  // frag row / k-chunk group

    f32x4 acc[4][4];
#pragma unroll
    for (int m = 0; m < 4; ++m)
#pragma unroll
        for (int n = 0; n < 4; ++n) acc[m][n] = f32x4{0.f, 0.f, 0.f, 0.f};

    const unsigned short* srcs[4] = {xhi + (size_t)i0 * D_DIM, xlo + (size_t)i0 * D_DIM,
                                     xhi + (size_t)j0 * D_DIM, xlo + (size_t)j0 * D_DIM};

    for (int kk = 0; kk < D_DIM; kk += 32) {
        // stage 4 tiles; linear LDS dest, inverse-swizzled global source (rule #21)
#pragma unroll
        for (int t = 0; t < 8; ++t) {
            int idx = t * 256 + tid;
            int tile = idx >> 9;
            int ci = idx & 511;
            int row = ci >> 2, c = ci & 3;
            int cg = c ^ swz_of(row);
            gload_lds16(srcs[tile] + (size_t)row * D_DIM + kk + cg * 8, lds + idx * 16);
        }
        __syncthreads();

        bf16x8 ah[4], al[4], bh[4], bl[4];
#pragma unroll
        for (int m = 0; m < 4; ++m) {
            int row = wr * 64 + m * 16 + lr;
            int off = row * 64 + ((lg ^ swz_of(row)) << 4);
            ah[m] = *(const bf16x8*)(lAh + off);
            al[m] = *(const bf16x8*)(lAl + off);
        }
#pragma unroll
        for (int n = 0; n < 4; ++n) {
            int row = wc * 64 + n * 16 + lr;
            int off = row * 64 + ((lg ^ swz_of(row)) << 4);
            bh[n] = *(const bf16x8*)(lBh + off);
            bl[n] = *(const bf16x8*)(lBl + off);
        }
#pragma unroll
        for (int m = 0; m < 4; ++m)
#pragma unroll
            for (int n = 0; n < 4; ++n) {
                acc[m][n] = __builtin_amdgcn_mfma_f32_16x16x32_bf16(ah[m], bh[n], acc[m][n], 0, 0, 0);
                acc[m][n] = __builtin_amdgcn_mfma_f32_16x16x32_bf16(ah[m], bl[n], acc[m][n], 0, 0, 0);
                acc[m][n] = __builtin_amdgcn_mfma_f32_16x16x32_bf16(al[m], bh[n], acc[m][n], 0, 0, 0);
            }
        __syncthreads();
    }

    // ---- epilogue ----
    // C/D layout (m89-verified): col = lane&15 (B-side row), row = (lane>>4)*4 + reg (A-side row)
    float sqi[4][4], wi[4][4], sqj[4], wj[4];
#pragma unroll
    for (int m = 0; m < 4; ++m)
#pragma unroll
        for (int j = 0; j < 4; ++j) {
            int i = i0 + wr * 64 + m * 16 + lg * 4 + j;
            sqi[m][j] = sq[i];
            wi[m][j] = (i < N_SRC) ? w[i] : 0.f;
        }
#pragma unroll
    for (int n = 0; n < 4; ++n) {
        int jg = j0 + wc * 64 + n * 16 + lr;
        sqj[n] = sq[jg];
        wj[n] = (jg < N_SRC) ? w[jg] : 0.f;
    }
    const float ib0 = invbw[0], ib1 = invbw[1], ib2 = invbw[2], ib3 = invbw[3], ib4 = invbw[4];

    const double C_SS = 1.0 / 8386560.0;   // n_s*(n_s-1)/2 == n_t*(n_t-1)/2
    const double C_ST = 2.0 / 16777216.0;  // 2/(n_s*n_t)
    const bool diag = (ti == tj);
    const int region = (tj < NT / 2) ? 0 : ((ti >= NT / 2) ? 1 : 2);  // 0=ss 1=tt 2=st

    double lsum = 0.0;
#pragma unroll
    for (int m = 0; m < 4; ++m)
#pragma unroll
        for (int n = 0; n < 4; ++n)
#pragma unroll
            for (int j = 0; j < 4; ++j) {
                int rg = wr * 64 + m * 16 + lg * 4 + j;     // local row in tile
                int cg = wc * 64 + n * 16 + lr;             // local col in tile
                if (diag && rg >= cg) continue;
                float l2 = fmaf(-2.f, acc[m][n][j], sqi[m][j] + sqj[n]);
                l2 = fmaxf(l2, 0.f);
                float k5 = __expf(-l2 * ib0) + __expf(-l2 * ib1) + __expf(-l2 * ib2) +
                           __expf(-l2 * ib3) + __expf(-l2 * ib4);
                float cf;
                if (region == 0)      cf = wi[m][j] * wj[n];
                else if (region == 1) cf = 1.f;
                else                  cf = wi[m][j];
                double term = (double)(k5 * cf);
                lsum += (region == 2) ? (-C_ST * term) : (C_SS * term);
            }

    __shared__ double sdl[256];
    sdl[tid] = lsum;
    __syncthreads();
    for (int off = 128; off; off >>= 1) {
        if (tid < off) sdl[tid] += sdl[tid + off];
        __syncthreads();
    }
    if (tid == 0) atomicAdd(&accum[2], sdl[0]);
}

__global__ void k_out(const double* __restrict__ accum, float* __restrict__ out) {
    if (threadIdx.x == 0) out[0] = (float)accum[2];
}

extern "C" void kernel_launch(void* const* d_in, const int* in_sizes, int n_in,
                              void* d_out, int out_size, void* d_ws, size_t ws_size,
                              hipStream_t stream) {
    const float* x    = (const float*)d_in[0];
    const float* imw  = (const float*)d_in[1];
    const int*   y    = (const int*)d_in[3];
    const int*   alph = (const int*)d_in[4];
    float* out = (float*)d_out;

    char* ws = (char*)d_ws;
    double* accum   = (double*)ws;
    float*  invbw   = (float*)(ws + 64);
    double* colsum  = (double*)(ws + 4096);
    float*  sq      = (float*)(ws + 8192);
    float*  wgt     = (float*)(ws + 40960);
    unsigned short* xhi = (unsigned short*)(ws + 65536);
    unsigned short* xlo = (unsigned short*)(ws + 65536 + (size_t)N_TOT * D_DIM * 2);

    hipMemsetAsync(d_ws, 0, 8192, stream);  // accum + colsum
    k_convert<<<N_TOT * D_DIM / (256 * 8), 256, 0, stream>>>(x, xhi, xlo);
    k_rowstats<<<N_TOT / 4, 256, 0, stream>>>(x, accum, sq);
    k_colsum<<<N_TOT / 128, 256, 0, stream>>>(x, colsum);
    k_weights<<<N_SRC / 256, 256, 0, stream>>>(imw, y, alph, wgt);
    k_bw<<<1, 64, 0, stream>>>(accum, colsum, invbw);
    k_pairs<<<NTILES, 256, 0, stream>>>(xhi, xlo, sq, wgt, invbw, accum);
    k_out<<<1, 64, 0, stream>>>(accum, out);
}

// Round 4
// 255.316 us; speedup vs baseline: 2.4469x; 1.0754x over previous
//
#include <hip/hip_runtime.h>
#include <math.h>

#define N_TOT 8192
#define N_SRC 4096
#define D_DIM 512
#define BM 128
#define NT (N_TOT / BM)            /* 64 tiles per dim */
#define NTILES (NT * (NT + 1) / 2) /* 2080 triangular tiles; 2080 % 8 == 0 */

typedef short bf16x8 __attribute__((ext_vector_type(8)));
typedef unsigned short u16x8 __attribute__((ext_vector_type(8)));
typedef float f32x4 __attribute__((ext_vector_type(4)));

// ws layout (bytes):
//   0     : double accum[4]   {0=sum of row-sq, 2=loss}
//   64    : float invbw[5]
//   4096  : double colsum[512]
//   8192  : float sq[8192]
//   40960 : float w[4096]
//   65536 : ushort xhi[8192*512]   (8 MB)
//   8454144: ushort xlo[8192*512]  (8 MB)

__device__ __forceinline__ unsigned short f2bf_rn(float v) {
    unsigned int u = __float_as_uint(v);
    unsigned int r = (u + 0x7FFFu + ((u >> 16) & 1u)) >> 16;
    return (unsigned short)r;
}

// One pass over x: bf16 hi/lo split + row sum-of-squares. Wave per row.
__global__ __launch_bounds__(256) void k_prep(const float* __restrict__ x,
                                              unsigned short* __restrict__ xhi,
                                              unsigned short* __restrict__ xlo,
                                              float* __restrict__ sq,
                                              double* __restrict__ accum) {
    const int wave = threadIdx.x >> 6;
    const int lane = threadIdx.x & 63;
    const int row = blockIdx.x * 4 + wave;
    const size_t base = (size_t)row * D_DIM + lane * 8;
    float v[8];
    *(float4*)&v[0] = *(const float4*)(x + base);
    *(float4*)&v[4] = *(const float4*)(x + base + 4);
    u16x8 h, l;
    float s = 0.f;
#pragma unroll
    for (int j = 0; j < 8; ++j) {
        unsigned short hb = f2bf_rn(v[j]);
        float hv = __uint_as_float(((unsigned int)hb) << 16);
        h[j] = hb;
        l[j] = f2bf_rn(v[j] - hv);
        s = fmaf(v[j], v[j], s);
    }
    *(u16x8*)(xhi + base) = h;
    *(u16x8*)(xlo + base) = l;
#pragma unroll
    for (int off = 32; off; off >>= 1) s += __shfl_xor(s, off);
    __shared__ float ls[4];
    if (lane == 0) { sq[row] = s; ls[wave] = s; }
    __syncthreads();
    if (threadIdx.x == 0) {
        double t = (double)ls[0] + (double)ls[1] + (double)ls[2] + (double)ls[3];
        atomicAdd(&accum[0], t);
    }
}

// 64 blocks x 128 rows, coalesced row reads; blocks 0-15 also compute weights.
__global__ __launch_bounds__(256) void k_colsum_w(const float* __restrict__ x,
                                                  double* __restrict__ colsum,
                                                  const float* __restrict__ imw,
                                                  const int* __restrict__ y,
                                                  const int* __restrict__ alpha_p,
                                                  float* __restrict__ w) {
    if (blockIdx.x < 16) {
        int i = blockIdx.x * 256 + threadIdx.x;
        float a = (float)alpha_p[0];
        w[i] = a * imw[y[i]] + (1.0f - a);
    }
    const int r0 = blockIdx.x * 128;
    const int c0 = threadIdx.x * 2;
    double s0 = 0.0, s1 = 0.0;
    for (int r = 0; r < 128; ++r) {
        float2 v = *(const float2*)(x + (size_t)(r0 + r) * D_DIM + c0);
        s0 += (double)v.x;
        s1 += (double)v.y;
    }
    atomicAdd(&colsum[c0], s0);
    atomicAdd(&colsum[c0 + 1], s1);
}

__global__ void k_bw(const double* __restrict__ accum,
                     const double* __restrict__ colsum,
                     float* __restrict__ invbw) {
    const int lane = threadIdx.x & 63;
    double s = 0.0;
    for (int c = lane; c < D_DIM; c += 64) {
        double v = colsum[c];
        s += v * v;
    }
#pragma unroll
    for (int off = 32; off; off >>= 1) s += __shfl_xor(s, off);
    if (lane == 0) {
        // sum of clamped l2 == analytic sum (clamp only trims diagonal fp noise)
        double sum_l2 = 2.0 * (double)N_TOT * accum[0] - 2.0 * s;
        double bw = sum_l2 / ((double)N_TOT * (double)N_TOT - (double)N_TOT);
        bw *= 0.25;  // / KERNEL_MUL^(KERNEL_NUM/2)
        double m = 1.0;
        for (int i = 0; i < 5; ++i) { invbw[i] = (float)(1.0 / (bw * m)); m *= 2.0; }
    }
}

__device__ __forceinline__ void gload_lds16(const unsigned short* g, char* l) {
    __builtin_amdgcn_global_load_lds((const __attribute__((address_space(1))) void*)g,
                                     (__attribute__((address_space(3))) void*)l,
                                     16, 0, 0);
}

// swizzle: chunk-of-16B index XOR'd with row bits -> 2-way max bank aliasing
__device__ __forceinline__ int swz_of(int row) { return (row & 3) ^ ((row >> 2) & 3); }

__global__ __launch_bounds__(256) void k_pairs(const unsigned short* __restrict__ xhi,
                                               const unsigned short* __restrict__ xlo,
                                               const float* __restrict__ sq,
                                               const float* __restrict__ w,
                                               const float* __restrict__ invbw,
                                               double* __restrict__ accum) {
    // XCD-chunked bijective remap (8 XCDs, 2080 % 8 == 0): consecutive remapped
    // ids land on one XCD -> shared A-panel stays in that XCD's L2.
    int bid = (blockIdx.x & 7) * (NTILES / 8) + (blockIdx.x >> 3);
    // triangular tile decode: (ti, tj), ti <= tj
    int ti = 0, rem = bid;
    while (rem >= NT - ti) { rem -= NT - ti; ++ti; }
    const int tj = ti + rem;
    const int i0 = ti * BM, j0 = tj * BM;

    // 4 swizzled tiles [128 rows][32 bf16] = 8 KB each: hiA, loA, hiB, loB
    __shared__ __align__(16) char lds[4 * 8192];
    char* lAh = lds;
    char* lAl = lds + 8192;
    char* lBh = lds + 16384;
    char* lBl = lds + 24576;

    const int tid = threadIdx.x;
    const int lane = tid & 63;
    const int wave = tid >> 6;
    const int wr = wave >> 1, wc = wave & 1;   // 2x2 wave quadrants, 64x64 each
    const int lr = lane & 15, lg = lane >> 4;  // frag row / k-chunk group

    f32x4 acc[4][4];
#pragma unroll
    for (int m = 0; m < 4; ++m)
#pragma unroll
        for (int n = 0; n < 4; ++n) acc[m][n] = f32x4{0.f, 0.f, 0.f, 0.f};

    const unsigned short* srcs[4] = {xhi + (size_t)i0 * D_DIM, xlo + (size_t)i0 * D_DIM,
                                     xhi + (size_t)j0 * D_DIM, xlo + (size_t)j0 * D_DIM};

    for (int kk = 0; kk < D_DIM; kk += 32) {
        // stage 4 tiles; linear LDS dest, inverse-swizzled global source (rule #21)
#pragma unroll
        for (int t = 0; t < 8; ++t) {
            int idx = t * 256 + tid;
            int tile = idx >> 9;
            int ci = idx & 511;
            int row = ci >> 2, c = ci & 3;
            int cg = c ^ swz_of(row);
            gload_lds16(srcs[tile] + (size_t)row * D_DIM + kk + cg * 8, lds + idx * 16);
        }
        __syncthreads();

        bf16x8 ah[4], al[4], bh[4], bl[4];
#pragma unroll
        for (int m = 0; m < 4; ++m) {
            int row = wr * 64 + m * 16 + lr;
            int off = row * 64 + ((lg ^ swz_of(row)) << 4);
            ah[m] = *(const bf16x8*)(lAh + off);
            al[m] = *(const bf16x8*)(lAl + off);
        }
#pragma unroll
        for (int n = 0; n < 4; ++n) {
            int row = wc * 64 + n * 16 + lr;
            int off = row * 64 + ((lg ^ swz_of(row)) << 4);
            bh[n] = *(const bf16x8*)(lBh + off);
            bl[n] = *(const bf16x8*)(lBl + off);
        }
#pragma unroll
        for (int m = 0; m < 4; ++m)
#pragma unroll
            for (int n = 0; n < 4; ++n) {
                acc[m][n] = __builtin_amdgcn_mfma_f32_16x16x32_bf16(ah[m], bh[n], acc[m][n], 0, 0, 0);
                acc[m][n] = __builtin_amdgcn_mfma_f32_16x16x32_bf16(ah[m], bl[n], acc[m][n], 0, 0, 0);
                acc[m][n] = __builtin_amdgcn_mfma_f32_16x16x32_bf16(al[m], bh[n], acc[m][n], 0, 0, 0);
            }
        __syncthreads();
    }

    // ---- epilogue ----
    // C/D layout (m89-verified): col = lane&15 (B-side row), row = (lane>>4)*4 + reg
    float sqi[4][4], wi[4][4], sqj[4], wj[4];
#pragma unroll
    for (int m = 0; m < 4; ++m)
#pragma unroll
        for (int j = 0; j < 4; ++j) {
            int i = i0 + wr * 64 + m * 16 + lg * 4 + j;
            sqi[m][j] = sq[i];
            wi[m][j] = (i < N_SRC) ? w[i] : 0.f;
        }
#pragma unroll
    for (int n = 0; n < 4; ++n) {
        int jg = j0 + wc * 64 + n * 16 + lr;
        sqj[n] = sq[jg];
        wj[n] = (jg < N_SRC) ? w[jg] : 0.f;
    }
    // geometric bandwidths: ib_i = ib0/2^i  ->  with t = exp(-l2*ib4):
    // k5 = t + t^2 + t^4 + t^8 + t^16   (1 exp instead of 5)
    const float nib4 = -invbw[4];

    const bool diag = (ti == tj);
    const int region = (tj < NT / 2) ? 0 : ((ti >= NT / 2) ? 1 : 2);  // 0=ss 1=tt 2=st

    float facc = 0.f;  // region uniform per block -> single fp32 accumulator
#pragma unroll
    for (int m = 0; m < 4; ++m)
#pragma unroll
        for (int n = 0; n < 4; ++n)
#pragma unroll
            for (int j = 0; j < 4; ++j) {
                int rg = wr * 64 + m * 16 + lg * 4 + j;     // local row in tile
                int cg = wc * 64 + n * 16 + lr;             // local col in tile
                if (diag && rg >= cg) continue;
                float l2 = fmaf(-2.f, acc[m][n][j], sqi[m][j] + sqj[n]);
                l2 = fmaxf(l2, 0.f);
                float t = __expf(l2 * nib4);
                float t2 = t * t, t4 = t2 * t2, t8 = t4 * t4, t16 = t8 * t8;
                float k5 = t + t2 + t4 + t8 + t16;
                float cf;
                if (region == 0)      cf = wi[m][j] * wj[n];
                else if (region == 1) cf = 1.f;
                else                  cf = wi[m][j];
                facc = fmaf(k5, cf, facc);
            }

    __shared__ double sdl[256];
    sdl[tid] = (double)facc;
    __syncthreads();
    for (int off = 128; off; off >>= 1) {
        if (tid < off) sdl[tid] += sdl[tid + off];
        __syncthreads();
    }
    if (tid == 0) {
        const double C_SS = 1.0 / 8386560.0;   // n_s*(n_s-1)/2 == n_t*(n_t-1)/2
        const double C_ST = 2.0 / 16777216.0;  // 2/(n_s*n_t)
        double scale = (region == 2) ? -C_ST : C_SS;
        atomicAdd(&accum[2], scale * sdl[0]);
    }
}

__global__ void k_out(const double* __restrict__ accum, float* __restrict__ out) {
    if (threadIdx.x == 0) out[0] = (float)accum[2];
}

extern "C" void kernel_launch(void* const* d_in, const int* in_sizes, int n_in,
                              void* d_out, int out_size, void* d_ws, size_t ws_size,
                              hipStream_t stream) {
    const float* x    = (const float*)d_in[0];
    const float* imw  = (const float*)d_in[1];
    const int*   y    = (const int*)d_in[3];
    const int*   alph = (const int*)d_in[4];
    float* out = (float*)d_out;

    char* ws = (char*)d_ws;
    double* accum   = (double*)ws;
    float*  invbw   = (float*)(ws + 64);
    double* colsum  = (double*)(ws + 4096);
    float*  sq      = (float*)(ws + 8192);
    float*  wgt     = (float*)(ws + 40960);
    unsigned short* xhi = (unsigned short*)(ws + 65536);
    unsigned short* xlo = (unsigned short*)(ws + 65536 + (size_t)N_TOT * D_DIM * 2);

    hipMemsetAsync(d_ws, 0, 8192, stream);  // accum + colsum
    k_prep<<<N_TOT / 4, 256, 0, stream>>>(x, xhi, xlo, sq, accum);
    k_colsum_w<<<N_TOT / 128, 256, 0, stream>>>(x, colsum, imw, y, alph, wgt);
    k_bw<<<1, 64, 0, stream>>>(accum, colsum, invbw);
    k_pairs<<<NTILES, 256, 0, stream>>>(xhi, xlo, sq, wgt, invbw, accum);
    k_out<<<1, 64, 0, stream>>>(accum, out);
}

// Round 5
// 244.043 us; speedup vs baseline: 2.5600x; 1.0462x over previous
//
#include <hip/hip_runtime.h>
#include <math.h>

#define N_TOT 8192
#define N_SRC 4096
#define D_DIM 512
#define BM 128
#define NT (N_TOT / BM)            /* 64 tiles per dim */
#define NTILES (NT * (NT + 1) / 2) /* 2080 triangular tiles; 2080 % 8 == 0 */

typedef short bf16x8 __attribute__((ext_vector_type(8)));
typedef unsigned short u16x8 __attribute__((ext_vector_type(8)));
typedef float f32x4 __attribute__((ext_vector_type(4)));

// ws layout (bytes):
//   0      : double accum[4]   {2=loss}
//   64     : unsigned int cnt
//   128    : float invbw[5]
//   4096   : float sq[8192]           (32 KB)
//   36864  : float w[4096]            (16 KB)
//   53248  : double colpart[64][512]  (256 KB)
//   315392 : ushort xhi[8192*512]     (8 MB)
//   8704000: ushort xlo[8192*512]     (8 MB)

__device__ __forceinline__ unsigned short f2bf_rn(float v) {
    unsigned int u = __float_as_uint(v);
    unsigned int r = (u + 0x7FFFu + ((u >> 16) & 1u)) >> 16;
    return (unsigned short)r;
}

// One pass over x: bf16 hi/lo split + row sum-of-squares. Wave per row.
__global__ __launch_bounds__(256) void k_prep(const float* __restrict__ x,
                                              unsigned short* __restrict__ xhi,
                                              unsigned short* __restrict__ xlo,
                                              float* __restrict__ sq) {
    const int wave = threadIdx.x >> 6;
    const int lane = threadIdx.x & 63;
    const int row = blockIdx.x * 4 + wave;
    const size_t base = (size_t)row * D_DIM + lane * 8;
    float v[8];
    *(float4*)&v[0] = *(const float4*)(x + base);
    *(float4*)&v[4] = *(const float4*)(x + base + 4);
    u16x8 h, l;
    float s = 0.f;
#pragma unroll
    for (int j = 0; j < 8; ++j) {
        unsigned short hb = f2bf_rn(v[j]);
        float hv = __uint_as_float(((unsigned int)hb) << 16);
        h[j] = hb;
        l[j] = f2bf_rn(v[j] - hv);
        s = fmaf(v[j], v[j], s);
    }
    *(u16x8*)(xhi + base) = h;
    *(u16x8*)(xlo + base) = l;
#pragma unroll
    for (int off = 32; off; off >>= 1) s += __shfl_xor(s, off);
    if (lane == 0) sq[row] = s;
}

// 64 blocks x 128 rows, coalesced row reads; own partial slot (no pre-zero).
// Blocks 0-15 also compute the class weights.
__global__ __launch_bounds__(256) void k_colsum_w(const float* __restrict__ x,
                                                  double* __restrict__ colpart,
                                                  const float* __restrict__ imw,
                                                  const int* __restrict__ y,
                                                  const int* __restrict__ alpha_p,
                                                  float* __restrict__ w) {
    if (blockIdx.x < 16) {
        int i = blockIdx.x * 256 + threadIdx.x;
        float a = (float)alpha_p[0];
        w[i] = a * imw[y[i]] + (1.0f - a);
    }
    const int r0 = blockIdx.x * 128;
    const int c0 = threadIdx.x * 2;
    double s0 = 0.0, s1 = 0.0;
    for (int r = 0; r < 128; ++r) {
        float2 v = *(const float2*)(x + (size_t)(r0 + r) * D_DIM + c0);
        s0 += (double)v.x;
        s1 += (double)v.y;
    }
    colpart[(size_t)blockIdx.x * D_DIM + c0]     = s0;
    colpart[(size_t)blockIdx.x * D_DIM + c0 + 1] = s1;
}

// Bandwidth from analytic sum; also zeroes the loss accumulator + counter.
__global__ __launch_bounds__(256) void k_bw(const float* __restrict__ sq,
                                            const double* __restrict__ colpart,
                                            float* __restrict__ invbw,
                                            double* __restrict__ accum,
                                            unsigned int* __restrict__ cnt) {
    const int tid = threadIdx.x;
    if (tid == 0) { accum[2] = 0.0; *cnt = 0u; }
    double s2 = 0.0;
    for (int i = tid; i < N_TOT; i += 256) s2 += (double)sq[i];
    double sc = 0.0;
    for (int c = tid; c < D_DIM; c += 256) {
        double cs = 0.0;
#pragma unroll 8
        for (int b = 0; b < 64; ++b) cs += colpart[(size_t)b * D_DIM + c];
        sc += cs * cs;
    }
    __shared__ double r1[256], r2[256];
    r1[tid] = s2; r2[tid] = sc;
    __syncthreads();
    for (int off = 128; off; off >>= 1) {
        if (tid < off) { r1[tid] += r1[tid + off]; r2[tid] += r2[tid + off]; }
        __syncthreads();
    }
    if (tid == 0) {
        // sum of clamped l2 == analytic sum (clamp only trims diagonal fp noise)
        double sum_l2 = 2.0 * (double)N_TOT * r1[0] - 2.0 * r2[0];
        double bw = sum_l2 / ((double)N_TOT * (double)N_TOT - (double)N_TOT);
        bw *= 0.25;  // / KERNEL_MUL^(KERNEL_NUM/2)
        double m = 1.0;
        for (int i = 0; i < 5; ++i) { invbw[i] = (float)(1.0 / (bw * m)); m *= 2.0; }
    }
}

__device__ __forceinline__ void gload_lds16(const unsigned short* g, char* l) {
    __builtin_amdgcn_global_load_lds((const __attribute__((address_space(1))) void*)g,
                                     (__attribute__((address_space(3))) void*)l,
                                     16, 0, 0);
}

// swizzle: chunk-of-16B index XOR'd with row bits -> 2-way max bank aliasing
__device__ __forceinline__ int swz_of(int row) { return (row & 3) ^ ((row >> 2) & 3); }

// 2-product split: G = (hiA + loA) . hiB = x_i . hi_j ; dropped x.loB term is
// zero-mean rms ~0.09 in l2 -> ~4e-8 on the loss (threshold 4.7e-6).
__global__ __launch_bounds__(256) void k_pairs(const unsigned short* __restrict__ xhi,
                                               const unsigned short* __restrict__ xlo,
                                               const float* __restrict__ sq,
                                               const float* __restrict__ w,
                                               const float* __restrict__ invbw,
                                               double* __restrict__ accum,
                                               unsigned int* __restrict__ cnt,
                                               float* __restrict__ out) {
    // XCD-chunked bijective remap (8 XCDs, 2080 % 8 == 0)
    int bid = (blockIdx.x & 7) * (NTILES / 8) + (blockIdx.x >> 3);
    int ti = 0, rem = bid;
    while (rem >= NT - ti) { rem -= NT - ti; ++ti; }
    const int tj = ti + rem;
    const int i0 = ti * BM, j0 = tj * BM;

    // 3 swizzled tiles [128 rows][32 bf16] = 8 KB each: hiA, loA, hiB
    __shared__ __align__(16) char lds[3 * 8192];
    __shared__ double sdl4[4];
    char* lAh = lds;
    char* lAl = lds + 8192;
    char* lBh = lds + 16384;

    const int tid = threadIdx.x;
    const int lane = tid & 63;
    const int wave = tid >> 6;
    const int wr = wave >> 1, wc = wave & 1;   // 2x2 wave quadrants, 64x64 each
    const int lr = lane & 15, lg = lane >> 4;  // frag row / k-chunk group

    f32x4 acc[4][4];
#pragma unroll
    for (int m = 0; m < 4; ++m)
#pragma unroll
        for (int n = 0; n < 4; ++n) acc[m][n] = f32x4{0.f, 0.f, 0.f, 0.f};

    const unsigned short* srcs[3] = {xhi + (size_t)i0 * D_DIM, xlo + (size_t)i0 * D_DIM,
                                     xhi + (size_t)j0 * D_DIM};

    for (int kk = 0; kk < D_DIM; kk += 32) {
        // stage 3 tiles; linear LDS dest, inverse-swizzled global source (rule #21)
#pragma unroll
        for (int t = 0; t < 6; ++t) {
            int idx = t * 256 + tid;
            int tile = idx >> 9;
            int ci = idx & 511;
            int row = ci >> 2, c = ci & 3;
            int cg = c ^ swz_of(row);
            gload_lds16(srcs[tile] + (size_t)row * D_DIM + kk + cg * 8, lds + idx * 16);
        }
        __syncthreads();

        bf16x8 ah[4], al[4], bh[4];
#pragma unroll
        for (int m = 0; m < 4; ++m) {
            int row = wr * 64 + m * 16 + lr;
            int off = row * 64 + ((lg ^ swz_of(row)) << 4);
            ah[m] = *(const bf16x8*)(lAh + off);
            al[m] = *(const bf16x8*)(lAl + off);
        }
#pragma unroll
        for (int n = 0; n < 4; ++n) {
            int row = wc * 64 + n * 16 + lr;
            int off = row * 64 + ((lg ^ swz_of(row)) << 4);
            bh[n] = *(const bf16x8*)(lBh + off);
        }
#pragma unroll
        for (int m = 0; m < 4; ++m)
#pragma unroll
            for (int n = 0; n < 4; ++n) {
                acc[m][n] = __builtin_amdgcn_mfma_f32_16x16x32_bf16(ah[m], bh[n], acc[m][n], 0, 0, 0);
                acc[m][n] = __builtin_amdgcn_mfma_f32_16x16x32_bf16(al[m], bh[n], acc[m][n], 0, 0, 0);
            }
        __syncthreads();
    }

    // ---- epilogue ----
    // C/D layout (m89-verified): col = lane&15 (B row), row = (lane>>4)*4 + reg
    float sqi[4][4], wi[4][4], sqj[4], wj[4];
#pragma unroll
    for (int m = 0; m < 4; ++m)
#pragma unroll
        for (int j = 0; j < 4; ++j) {
            int i = i0 + wr * 64 + m * 16 + lg * 4 + j;
            sqi[m][j] = sq[i];
            wi[m][j] = (i < N_SRC) ? w[i] : 0.f;
        }
#pragma unroll
    for (int n = 0; n < 4; ++n) {
        int jg = j0 + wc * 64 + n * 16 + lr;
        sqj[n] = sq[jg];
        wj[n] = (jg < N_SRC) ? w[jg] : 0.f;
    }
    // geometric bandwidths: with t = exp(-l2*ib4): k5 = t + t^2 + t^4 + t^8 + t^16
    const float nib4 = -invbw[4];

    const bool diag = (ti == tj);
    const int region = (tj < NT / 2) ? 0 : ((ti >= NT / 2) ? 1 : 2);  // 0=ss 1=tt 2=st

    float facc = 0.f;  // region uniform per block -> single fp32 accumulator
#pragma unroll
    for (int m = 0; m < 4; ++m)
#pragma unroll
        for (int n = 0; n < 4; ++n)
#pragma unroll
            for (int j = 0; j < 4; ++j) {
                int rg = wr * 64 + m * 16 + lg * 4 + j;
                int cg = wc * 64 + n * 16 + lr;
                if (diag && rg >= cg) continue;
                float l2 = fmaf(-2.f, acc[m][n][j], sqi[m][j] + sqj[n]);
                l2 = fmaxf(l2, 0.f);
                float t = __expf(l2 * nib4);
                float t2 = t * t, t4 = t2 * t2, t8 = t4 * t4, t16 = t8 * t8;
                float k5 = t + t2 + t4 + t8 + t16;
                float cf;
                if (region == 0)      cf = wi[m][j] * wj[n];
                else if (region == 1) cf = 1.f;
                else                  cf = wi[m][j];
                facc = fmaf(k5, cf, facc);
            }

    // wave shuffle-reduce, then 4-entry LDS combine, one atomic per block
#pragma unroll
    for (int off = 32; off; off >>= 1) facc += __shfl_xor(facc, off);
    if (lane == 0) sdl4[wave] = (double)facc;
    __syncthreads();
    if (tid == 0) {
        const double C_SS = 1.0 / 8386560.0;   // n_s*(n_s-1)/2 == n_t*(n_t-1)/2
        const double C_ST = 2.0 / 16777216.0;  // 2/(n_s*n_t)
        double scale = (region == 2) ? -C_ST : C_SS;
        atomicAdd(&accum[2], scale * (sdl4[0] + sdl4[1] + sdl4[2] + sdl4[3]));
        __threadfence();
        unsigned int old = atomicAdd(cnt, 1u);
        if (old == NTILES - 1) {
            double v = atomicAdd(&accum[2], 0.0);  // device-scope coherent read
            out[0] = (float)v;
        }
    }
}

extern "C" void kernel_launch(void* const* d_in, const int* in_sizes, int n_in,
                              void* d_out, int out_size, void* d_ws, size_t ws_size,
                              hipStream_t stream) {
    const float* x    = (const float*)d_in[0];
    const float* imw  = (const float*)d_in[1];
    const int*   y    = (const int*)d_in[3];
    const int*   alph = (const int*)d_in[4];
    float* out = (float*)d_out;

    char* ws = (char*)d_ws;
    double*       accum   = (double*)ws;
    unsigned int* cnt     = (unsigned int*)(ws + 64);
    float*        invbw   = (float*)(ws + 128);
    float*        sq      = (float*)(ws + 4096);
    float*        wgt     = (float*)(ws + 36864);
    double*       colpart = (double*)(ws + 53248);
    unsigned short* xhi   = (unsigned short*)(ws + 315392);
    unsigned short* xlo   = (unsigned short*)(ws + 8704000);

    k_prep<<<N_TOT / 4, 256, 0, stream>>>(x, xhi, xlo, sq);
    k_colsum_w<<<N_TOT / 128, 256, 0, stream>>>(x, colpart, imw, y, alph, wgt);
    k_bw<<<1, 256, 0, stream>>>(sq, colpart, invbw, accum, cnt);
    k_pairs<<<NTILES, 256, 0, stream>>>(xhi, xlo, sq, wgt, invbw, accum, cnt, out);
}

// Round 6
// 217.738 us; speedup vs baseline: 2.8692x; 1.1208x over previous
//
#include <hip/hip_runtime.h>
#include <math.h>

#define N_TOT 8192
#define N_SRC 4096
#define D_DIM 512
#define BM 128
#define NT (N_TOT / BM)            /* 64 tiles per dim */
#define NTILES (NT * (NT + 1) / 2) /* 2080 triangular tiles; 2080 % 8 == 0 */
#define NPREP 256                  /* k_prep blocks, 32 rows each */

typedef short bf16x8 __attribute__((ext_vector_type(8)));
typedef unsigned short u16x8 __attribute__((ext_vector_type(8)));
typedef float f32x4 __attribute__((ext_vector_type(4)));

// ws layout (bytes):
//   0      : double accum[4]   {2=loss}
//   64     : unsigned int cnt
//   128    : float invbw[5]
//   4096   : float sq[8192]             (32 KB)
//   36864  : float w[4096]              (16 KB)
//   53248  : float colpart[256][512]    (512 KB)
//   577536 : ushort xhi[8192*512]       (8 MB)
//   8966144: ushort xlo[8192*512]       (8 MB)

__device__ __forceinline__ unsigned short f2bf_rn(float v) {
    unsigned int u = __float_as_uint(v);
    unsigned int r = (u + 0x7FFFu + ((u >> 16) & 1u)) >> 16;
    return (unsigned short)r;
}

// One pass over x: bf16 hi/lo split + row sum-of-squares + column-sum partials.
// 256 blocks x 32 rows; wave per row (8 rows/wave); lane owns cols lane*8..+7.
__global__ __launch_bounds__(256) void k_prep(const float* __restrict__ x,
                                              unsigned short* __restrict__ xhi,
                                              unsigned short* __restrict__ xlo,
                                              float* __restrict__ sq,
                                              float* __restrict__ colpart) {
    const int wave = threadIdx.x >> 6;
    const int lane = threadIdx.x & 63;
    __shared__ float colbuf[4][512];
    float fcol[8];
#pragma unroll
    for (int j = 0; j < 8; ++j) fcol[j] = 0.f;

#pragma unroll
    for (int r8 = 0; r8 < 8; ++r8) {
        const int row = blockIdx.x * 32 + wave * 8 + r8;
        const size_t base = (size_t)row * D_DIM + lane * 8;
        float v[8];
        *(float4*)&v[0] = *(const float4*)(x + base);
        *(float4*)&v[4] = *(const float4*)(x + base + 4);
        u16x8 h, l;
        float s = 0.f;
#pragma unroll
        for (int j = 0; j < 8; ++j) {
            unsigned short hb = f2bf_rn(v[j]);
            float hv = __uint_as_float(((unsigned int)hb) << 16);
            h[j] = hb;
            l[j] = f2bf_rn(v[j] - hv);
            s = fmaf(v[j], v[j], s);
            fcol[j] += v[j];
        }
        *(u16x8*)(xhi + base) = h;
        *(u16x8*)(xlo + base) = l;
#pragma unroll
        for (int off = 32; off; off >>= 1) s += __shfl_xor(s, off);
        if (lane == 0) sq[row] = s;
    }
#pragma unroll
    for (int j = 0; j < 8; ++j) colbuf[wave][lane * 8 + j] = fcol[j];
    __syncthreads();
    const int c = threadIdx.x * 2;
    float2 r;
    r.x = colbuf[0][c] + colbuf[1][c] + colbuf[2][c] + colbuf[3][c];
    r.y = colbuf[0][c + 1] + colbuf[1][c + 1] + colbuf[2][c + 1] + colbuf[3][c + 1];
    *(float2*)(colpart + (size_t)blockIdx.x * D_DIM + c) = r;
}

// Bandwidth from analytic sum; also weights + zeroing of loss accumulator.
__global__ __launch_bounds__(256) void k_bw(const float* __restrict__ sq,
                                            const float* __restrict__ colpart,
                                            const float* __restrict__ imw,
                                            const int* __restrict__ y,
                                            const int* __restrict__ alpha_p,
                                            float* __restrict__ w,
                                            float* __restrict__ invbw,
                                            double* __restrict__ accum,
                                            unsigned int* __restrict__ cnt) {
    const int tid = threadIdx.x;
    if (tid == 0) { accum[2] = 0.0; *cnt = 0u; }
    const float a = (float)alpha_p[0];
    for (int i = tid; i < N_SRC; i += 256) w[i] = a * imw[y[i]] + (1.0f - a);
    double s2 = 0.0;
    for (int i = tid; i < N_TOT; i += 256) s2 += (double)sq[i];
    double cs0 = 0.0, cs1 = 0.0;
    const int c = tid * 2;
#pragma unroll 8
    for (int b = 0; b < NPREP; ++b) {
        float2 v = *(const float2*)(colpart + (size_t)b * D_DIM + c);
        cs0 += (double)v.x;
        cs1 += (double)v.y;
    }
    double sc = cs0 * cs0 + cs1 * cs1;
    __shared__ double r1[256], r2[256];
    r1[tid] = s2; r2[tid] = sc;
    __syncthreads();
    for (int off = 128; off; off >>= 1) {
        if (tid < off) { r1[tid] += r1[tid + off]; r2[tid] += r2[tid + off]; }
        __syncthreads();
    }
    if (tid == 0) {
        // sum of clamped l2 == analytic sum (clamp only trims diagonal fp noise)
        double sum_l2 = 2.0 * (double)N_TOT * r1[0] - 2.0 * r2[0];
        double bw = sum_l2 / ((double)N_TOT * (double)N_TOT - (double)N_TOT);
        bw *= 0.25;  // / KERNEL_MUL^(KERNEL_NUM/2)
        double m = 1.0;
        for (int i = 0; i < 5; ++i) { invbw[i] = (float)(1.0 / (bw * m)); m *= 2.0; }
    }
}

__device__ __forceinline__ void gload_lds16(const unsigned short* g, char* l) {
    __builtin_amdgcn_global_load_lds((const __attribute__((address_space(1))) void*)g,
                                     (__attribute__((address_space(3))) void*)l,
                                     16, 0, 0);
}

// swizzle: chunk-of-16B index XOR'd with row bits -> 2-way max bank aliasing
__device__ __forceinline__ int swz_of(int row) { return (row & 3) ^ ((row >> 2) & 3); }

// 2-product split: G = (hiA + loA) . hiB = x_i . hi_j (x.loB dropped: ~4e-8 on loss).
// Double-buffered LDS pipeline: stage(t+1) issued before compute(t); counted
// waits + raw barrier keep prefetch in flight across the barrier (T3/T4-lite).
__global__ __launch_bounds__(256, 3) void k_pairs(const unsigned short* __restrict__ xhi,
                                                  const unsigned short* __restrict__ xlo,
                                                  const float* __restrict__ sq,
                                                  const float* __restrict__ w,
                                                  const float* __restrict__ invbw,
                                                  double* __restrict__ accum,
                                                  unsigned int* __restrict__ cnt,
                                                  float* __restrict__ out) {
    // XCD-chunked bijective remap (8 XCDs, 2080 % 8 == 0)
    int bid = (blockIdx.x & 7) * (NTILES / 8) + (blockIdx.x >> 3);
    int ti = 0, rem = bid;
    while (rem >= NT - ti) { rem -= NT - ti; ++ti; }
    const int tj = ti + rem;
    const int i0 = ti * BM, j0 = tj * BM;

    // 2 buffers x 3 swizzled tiles [128][32] bf16 (8 KB each: hiA, loA, hiB)
    __shared__ __align__(16) char lds[2 * 24576];
    __shared__ double sdl4[4];

    const int tid = threadIdx.x;
    const int lane = tid & 63;
    const int wave = tid >> 6;
    const int wr = wave >> 1, wc = wave & 1;   // 2x2 wave quadrants, 64x64 each
    const int lr = lane & 15, lg = lane >> 4;  // frag row / k-chunk group

    f32x4 acc[4][4];
#pragma unroll
    for (int m = 0; m < 4; ++m)
#pragma unroll
        for (int n = 0; n < 4; ++n) acc[m][n] = f32x4{0.f, 0.f, 0.f, 0.f};

    const unsigned short* srcs[3] = {xhi + (size_t)i0 * D_DIM, xlo + (size_t)i0 * D_DIM,
                                     xhi + (size_t)j0 * D_DIM};

#define STAGE(P, KK)                                                                   \
    do {                                                                               \
        _Pragma("unroll") for (int t6 = 0; t6 < 6; ++t6) {                             \
            int idx = t6 * 256 + tid;                                                  \
            int tile = idx >> 9;                                                       \
            int ci = idx & 511;                                                        \
            int row = ci >> 2, cc = ci & 3;                                            \
            int cg = cc ^ swz_of(row);                                                 \
            gload_lds16(srcs[tile] + (size_t)row * D_DIM + (KK) + cg * 8,              \
                        lds + (P) * 24576 + idx * 16);                                 \
        }                                                                              \
    } while (0)

    // prologue: fill buffer 0
    STAGE(0, 0);
    asm volatile("s_waitcnt vmcnt(0)\n\ts_barrier" ::: "memory");
    __builtin_amdgcn_sched_barrier(0);

#pragma unroll
    for (int t = 0; t < 16; ++t) {
        const int cur = t & 1;
        if (t < 15) STAGE(cur ^ 1, (t + 1) * 32);  // prefetch next K-step

        const char* lAh = lds + cur * 24576;
        const char* lAl = lAh + 8192;
        const char* lBh = lAh + 16384;
        bf16x8 ah[4], al[4], bh[4];
#pragma unroll
        for (int m = 0; m < 4; ++m) {
            int row = wr * 64 + m * 16 + lr;
            int off = row * 64 + ((lg ^ swz_of(row)) << 4);
            ah[m] = *(const bf16x8*)(lAh + off);
            al[m] = *(const bf16x8*)(lAl + off);
        }
#pragma unroll
        for (int n = 0; n < 4; ++n) {
            int row = wc * 64 + n * 16 + lr;
            int off = row * 64 + ((lg ^ swz_of(row)) << 4);
            bh[n] = *(const bf16x8*)(lBh + off);
        }
        __builtin_amdgcn_s_setprio(1);
#pragma unroll
        for (int m = 0; m < 4; ++m)
#pragma unroll
            for (int n = 0; n < 4; ++n) {
                acc[m][n] = __builtin_amdgcn_mfma_f32_16x16x32_bf16(ah[m], bh[n], acc[m][n], 0, 0, 0);
                acc[m][n] = __builtin_amdgcn_mfma_f32_16x16x32_bf16(al[m], bh[n], acc[m][n], 0, 0, 0);
            }
        __builtin_amdgcn_s_setprio(0);
        // all my ds_reads done (so next STAGE may overwrite), prefetch landed:
        asm volatile("s_waitcnt lgkmcnt(0)" ::: "memory");
        __builtin_amdgcn_sched_barrier(0);
        asm volatile("s_waitcnt vmcnt(0)\n\ts_barrier" ::: "memory");
        __builtin_amdgcn_sched_barrier(0);
    }
#undef STAGE

    // ---- epilogue ----
    // C/D layout (m89-verified): col = lane&15 (B row), row = (lane>>4)*4 + reg
    float sqi[4][4], wi[4][4], sqj[4], wj[4];
#pragma unroll
    for (int m = 0; m < 4; ++m)
#pragma unroll
        for (int j = 0; j < 4; ++j) {
            int i = i0 + wr * 64 + m * 16 + lg * 4 + j;
            sqi[m][j] = sq[i];
            wi[m][j] = (i < N_SRC) ? w[i] : 0.f;
        }
#pragma unroll
    for (int n = 0; n < 4; ++n) {
        int jg = j0 + wc * 64 + n * 16 + lr;
        sqj[n] = sq[jg];
        wj[n] = (jg < N_SRC) ? w[jg] : 0.f;
    }
    // geometric bandwidths: with t = exp(-l2*ib4): k5 = t + t^2 + t^4 + t^8 + t^16
    const float nib4 = -invbw[4];

    const bool diag = (ti == tj);
    const int region = (tj < NT / 2) ? 0 : ((ti >= NT / 2) ? 1 : 2);  // 0=ss 1=tt 2=st

    float facc = 0.f;  // region uniform per block -> single fp32 accumulator
#pragma unroll
    for (int m = 0; m < 4; ++m)
#pragma unroll
        for (int n = 0; n < 4; ++n)
#pragma unroll
            for (int j = 0; j < 4; ++j) {
                int rg = wr * 64 + m * 16 + lg * 4 + j;
                int cg = wc * 64 + n * 16 + lr;
                if (diag && rg >= cg) continue;
                float l2 = fmaf(-2.f, acc[m][n][j], sqi[m][j] + sqj[n]);
                l2 = fmaxf(l2, 0.f);
                float t = __expf(l2 * nib4);
                float t2 = t * t, t4 = t2 * t2, t8 = t4 * t4, t16 = t8 * t8;
                float k5 = t + t2 + t4 + t8 + t16;
                float cf;
                if (region == 0)      cf = wi[m][j] * wj[n];
                else if (region == 1) cf = 1.f;
                else                  cf = wi[m][j];
                facc = fmaf(k5, cf, facc);
            }

    // wave shuffle-reduce, then 4-entry LDS combine, one atomic per block
#pragma unroll
    for (int off = 32; off; off >>= 1) facc += __shfl_xor(facc, off);
    if (lane == 0) sdl4[wave] = (double)facc;
    __syncthreads();
    if (tid == 0) {
        const double C_SS = 1.0 / 8386560.0;   // n_s*(n_s-1)/2 == n_t*(n_t-1)/2
        const double C_ST = 2.0 / 16777216.0;  // 2/(n_s*n_t)
        double scale = (region == 2) ? -C_ST : C_SS;
        atomicAdd(&accum[2], scale * (sdl4[0] + sdl4[1] + sdl4[2] + sdl4[3]));
        __threadfence();
        unsigned int old = atomicAdd(cnt, 1u);
        if (old == NTILES - 1) {
            double v = atomicAdd(&accum[2], 0.0);  // device-scope coherent read
            out[0] = (float)v;
        }
    }
}

extern "C" void kernel_launch(void* const* d_in, const int* in_sizes, int n_in,
                              void* d_out, int out_size, void* d_ws, size_t ws_size,
                              hipStream_t stream) {
    const float* x    = (const float*)d_in[0];
    const float* imw  = (const float*)d_in[1];
    const int*   y    = (const int*)d_in[3];
    const int*   alph = (const int*)d_in[4];
    float* out = (float*)d_out;

    char* ws = (char*)d_ws;
    double*       accum   = (double*)ws;
    unsigned int* cnt     = (unsigned int*)(ws + 64);
    float*        invbw   = (float*)(ws + 128);
    float*        sq      = (float*)(ws + 4096);
    float*        wgt     = (float*)(ws + 36864);
    float*        colpart = (float*)(ws + 53248);
    unsigned short* xhi   = (unsigned short*)(ws + 577536);
    unsigned short* xlo   = (unsigned short*)(ws + 8966144);

    k_prep<<<NPREP, 256, 0, stream>>>(x, xhi, xlo, sq, colpart);
    k_bw<<<1, 256, 0, stream>>>(sq, colpart, imw, y, alph, wgt, invbw, accum, cnt);
    k_pairs<<<NTILES, 256, 0, stream>>>(xhi, xlo, sq, wgt, invbw, accum, cnt, out);
}

// Round 7
// 188.206 us; speedup vs baseline: 3.3195x; 1.1569x over previous
//
#include <hip/hip_runtime.h>
#include <math.h>

#define N_TOT 8192
#define N_SRC 4096
#define D_DIM 512
#define BM 128
#define NT (N_TOT / BM)            /* 64 tiles per dim */
#define NTILES (NT * (NT + 1) / 2) /* 2080 triangular tiles; 2080 % 8 == 0 */
#define NPREP 256                  /* k_prep blocks, 32 rows each */

typedef short bf16x8 __attribute__((ext_vector_type(8)));
typedef unsigned short u16x8 __attribute__((ext_vector_type(8)));
typedef float f32x4 __attribute__((ext_vector_type(4)));

// ws layout (bytes):
//   0      : double accum[4]   {2=loss}
//   64     : unsigned int cnt
//   128    : float invbw[5]
//   4096   : float sq[8192]             (32 KB)
//   36864  : float w[4096]              (16 KB)
//   53248  : float colpart[256][512]    (512 KB)
//   577536 : ushort xhi[8192*512]       (8 MB)

__device__ __forceinline__ unsigned short f2bf_rn(float v) {
    unsigned int u = __float_as_uint(v);
    unsigned int r = (u + 0x7FFFu + ((u >> 16) & 1u)) >> 16;
    return (unsigned short)r;
}

// One pass over x: bf16 round + row sum-of-squares + column-sum partials.
// 256 blocks x 32 rows; wave per 8 rows; lane owns cols lane*8..+7.
__global__ __launch_bounds__(256) void k_prep(const float* __restrict__ x,
                                              unsigned short* __restrict__ xhi,
                                              float* __restrict__ sq,
                                              float* __restrict__ colpart) {
    const int wave = threadIdx.x >> 6;
    const int lane = threadIdx.x & 63;
    __shared__ float colbuf[4][512];
    float fcol[8];
#pragma unroll
    for (int j = 0; j < 8; ++j) fcol[j] = 0.f;

#pragma unroll
    for (int r8 = 0; r8 < 8; ++r8) {
        const int row = blockIdx.x * 32 + wave * 8 + r8;
        const size_t base = (size_t)row * D_DIM + lane * 8;
        float v[8];
        *(float4*)&v[0] = *(const float4*)(x + base);
        *(float4*)&v[4] = *(const float4*)(x + base + 4);
        u16x8 h;
        float s = 0.f;
#pragma unroll
        for (int j = 0; j < 8; ++j) {
            h[j] = f2bf_rn(v[j]);
            s = fmaf(v[j], v[j], s);
            fcol[j] += v[j];
        }
        *(u16x8*)(xhi + base) = h;
#pragma unroll
        for (int off = 32; off; off >>= 1) s += __shfl_xor(s, off);
        if (lane == 0) sq[row] = s;
    }
#pragma unroll
    for (int j = 0; j < 8; ++j) colbuf[wave][lane * 8 + j] = fcol[j];
    __syncthreads();
    const int c = threadIdx.x * 2;
    float2 r;
    r.x = colbuf[0][c] + colbuf[1][c] + colbuf[2][c] + colbuf[3][c];
    r.y = colbuf[0][c + 1] + colbuf[1][c + 1] + colbuf[2][c + 1] + colbuf[3][c + 1];
    *(float2*)(colpart + (size_t)blockIdx.x * D_DIM + c) = r;
}

// Bandwidth from analytic sum; also weights + zeroing of loss accumulator.
__global__ __launch_bounds__(256) void k_bw(const float* __restrict__ sq,
                                            const float* __restrict__ colpart,
                                            const float* __restrict__ imw,
                                            const int* __restrict__ y,
                                            const int* __restrict__ alpha_p,
                                            float* __restrict__ w,
                                            float* __restrict__ invbw,
                                            double* __restrict__ accum,
                                            unsigned int* __restrict__ cnt) {
    const int tid = threadIdx.x;
    if (tid == 0) { accum[2] = 0.0; *cnt = 0u; }
    const float a = (float)alpha_p[0];
    for (int i = tid; i < N_SRC; i += 256) w[i] = a * imw[y[i]] + (1.0f - a);
    double s2 = 0.0;
    for (int i = tid; i < N_TOT; i += 256) s2 += (double)sq[i];
    double cs0 = 0.0, cs1 = 0.0;
    const int c = tid * 2;
#pragma unroll 8
    for (int b = 0; b < NPREP; ++b) {
        float2 v = *(const float2*)(colpart + (size_t)b * D_DIM + c);
        cs0 += (double)v.x;
        cs1 += (double)v.y;
    }
    double sc = cs0 * cs0 + cs1 * cs1;
    __shared__ double r1[256], r2[256];
    r1[tid] = s2; r2[tid] = sc;
    __syncthreads();
    for (int off = 128; off; off >>= 1) {
        if (tid < off) { r1[tid] += r1[tid + off]; r2[tid] += r2[tid + off]; }
        __syncthreads();
    }
    if (tid == 0) {
        // sum of clamped l2 == analytic sum (clamp only trims diagonal fp noise)
        double sum_l2 = 2.0 * (double)N_TOT * r1[0] - 2.0 * r2[0];
        double bw = sum_l2 / ((double)N_TOT * (double)N_TOT - (double)N_TOT);
        bw *= 0.25;  // / KERNEL_MUL^(KERNEL_NUM/2)
        double m = 1.0;
        for (int i = 0; i < 5; ++i) { invbw[i] = (float)(1.0 / (bw * m)); m *= 2.0; }
    }
}

__device__ __forceinline__ void gload_lds16(const unsigned short* g, char* l) {
    __builtin_amdgcn_global_load_lds((const __attribute__((address_space(1))) void*)g,
                                     (__attribute__((address_space(3))) void*)l,
                                     16, 0, 0);
}

// swizzle: chunk-of-16B index XOR'd with row bits -> 2-way max bank aliasing
__device__ __forceinline__ int swz_of(int row) { return (row & 3) ^ ((row >> 2) & 3); }

// hi-only Gram: G = hi_i . hi_j. l2 noise rms ~0.07 (vs l2~1e3) -> <=1e-7 on loss.
// Triple-buffered 2-deep pipeline: step t stages buf(t+2), computes buf(t),
// waits vmcnt(4) (never 0 mid-loop) -> 4 loads stay in flight across barrier.
__global__ __launch_bounds__(256, 3) void k_pairs(const unsigned short* __restrict__ xhi,
                                                  const float* __restrict__ sq,
                                                  const float* __restrict__ w,
                                                  const float* __restrict__ invbw,
                                                  double* __restrict__ accum,
                                                  unsigned int* __restrict__ cnt,
                                                  float* __restrict__ out) {
    // XCD-chunked bijective remap (8 XCDs, 2080 % 8 == 0)
    int bid = (blockIdx.x & 7) * (NTILES / 8) + (blockIdx.x >> 3);
    int ti = 0, rem = bid;
    while (rem >= NT - ti) { rem -= NT - ti; ++ti; }
    const int tj = ti + rem;
    const int i0 = ti * BM, j0 = tj * BM;

    // 3 buffers x 2 swizzled tiles [128][32] bf16 (8 KB each: hiA, hiB)
    __shared__ __align__(16) char lds[3 * 16384];
    __shared__ double sdl4[4];

    const int tid = threadIdx.x;
    const int lane = tid & 63;
    const int wave = tid >> 6;
    const int wr = wave >> 1, wc = wave & 1;   // 2x2 wave quadrants, 64x64 each
    const int lr = lane & 15, lg = lane >> 4;  // frag row / k-chunk group

    f32x4 acc[4][4];
#pragma unroll
    for (int m = 0; m < 4; ++m)
#pragma unroll
        for (int n = 0; n < 4; ++n) acc[m][n] = f32x4{0.f, 0.f, 0.f, 0.f};

    const unsigned short* srcs[2] = {xhi + (size_t)i0 * D_DIM, xhi + (size_t)j0 * D_DIM};

#define STAGE(P, KK)                                                                   \
    do {                                                                               \
        _Pragma("unroll") for (int t4 = 0; t4 < 4; ++t4) {                             \
            int idx = t4 * 256 + tid;                                                  \
            int tile = idx >> 9;                                                       \
            int ci = idx & 511;                                                        \
            int row = ci >> 2, cc = ci & 3;                                            \
            int cg = cc ^ swz_of(row);                                                 \
            gload_lds16(srcs[tile] + (size_t)row * D_DIM + (KK) + cg * 8,              \
                        lds + (P) * 16384 + idx * 16);                                 \
        }                                                                              \
    } while (0)

    // prologue: fill buffers 0,1; wait only for buffer 0 (vmcnt(4) leaves buf1's
    // 4 loads in flight)
    STAGE(0, 0);
    STAGE(1, 32);
    asm volatile("s_waitcnt vmcnt(4)\n\ts_barrier" ::: "memory");
    __builtin_amdgcn_sched_barrier(0);

#pragma unroll
    for (int t = 0; t < 16; ++t) {
        const int cur = t % 3;
        if (t < 14) STAGE((t + 2) % 3, (t + 2) * 32);  // 2-deep prefetch

        const char* lAh = lds + cur * 16384;
        const char* lBh = lAh + 8192;
        bf16x8 ah[4], bh[4];
#pragma unroll
        for (int m = 0; m < 4; ++m) {
            int row = wr * 64 + m * 16 + lr;
            int off = row * 64 + ((lg ^ swz_of(row)) << 4);
            ah[m] = *(const bf16x8*)(lAh + off);
        }
#pragma unroll
        for (int n = 0; n < 4; ++n) {
            int row = wc * 64 + n * 16 + lr;
            int off = row * 64 + ((lg ^ swz_of(row)) << 4);
            bh[n] = *(const bf16x8*)(lBh + off);
        }
        __builtin_amdgcn_s_setprio(1);
#pragma unroll
        for (int m = 0; m < 4; ++m)
#pragma unroll
            for (int n = 0; n < 4; ++n)
                acc[m][n] = __builtin_amdgcn_mfma_f32_16x16x32_bf16(ah[m], bh[n], acc[m][n], 0, 0, 0);
        __builtin_amdgcn_s_setprio(0);

        if (t < 14) {
            // my ds_reads done; buf(t+1) landed (drain to 4 = newest STAGE only)
            asm volatile("s_waitcnt lgkmcnt(0) vmcnt(4)\n\ts_barrier" ::: "memory");
            __builtin_amdgcn_sched_barrier(0);
        } else if (t == 14) {
            asm volatile("s_waitcnt lgkmcnt(0) vmcnt(0)\n\ts_barrier" ::: "memory");
            __builtin_amdgcn_sched_barrier(0);
        }
        // t == 15: last tile, no barrier needed (epilogue syncs itself)
    }
#undef STAGE

    // ---- epilogue ----
    // C/D layout (m89-verified): col = lane&15 (B row), row = (lane>>4)*4 + reg
    float sqi[4][4], wi[4][4], sqj[4], wj[4];
#pragma unroll
    for (int m = 0; m < 4; ++m)
#pragma unroll
        for (int j = 0; j < 4; ++j) {
            int i = i0 + wr * 64 + m * 16 + lg * 4 + j;
            sqi[m][j] = sq[i];
            wi[m][j] = (i < N_SRC) ? w[i] : 0.f;
        }
#pragma unroll
    for (int n = 0; n < 4; ++n) {
        int jg = j0 + wc * 64 + n * 16 + lr;
        sqj[n] = sq[jg];
        wj[n] = (jg < N_SRC) ? w[jg] : 0.f;
    }
    // geometric bandwidths: with t = exp(-l2*ib4): k5 = t + t^2 + t^4 + t^8 + t^16
    const float nib4 = -invbw[4];

    const bool diag = (ti == tj);
    const int region = (tj < NT / 2) ? 0 : ((ti >= NT / 2) ? 1 : 2);  // 0=ss 1=tt 2=st

    float facc = 0.f;  // region uniform per block -> single fp32 accumulator
#pragma unroll
    for (int m = 0; m < 4; ++m)
#pragma unroll
        for (int n = 0; n < 4; ++n)
#pragma unroll
            for (int j = 0; j < 4; ++j) {
                int rg = wr * 64 + m * 16 + lg * 4 + j;
                int cg = wc * 64 + n * 16 + lr;
                if (diag && rg >= cg) continue;
                float l2 = fmaf(-2.f, acc[m][n][j], sqi[m][j] + sqj[n]);
                l2 = fmaxf(l2, 0.f);
                float t = __expf(l2 * nib4);
                float t2 = t * t, t4 = t2 * t2, t8 = t4 * t4, t16 = t8 * t8;
                float k5 = t + t2 + t4 + t8 + t16;
                float cf;
                if (region == 0)      cf = wi[m][j] * wj[n];
                else if (region == 1) cf = 1.f;
                else                  cf = wi[m][j];
                facc = fmaf(k5, cf, facc);
            }

    // wave shuffle-reduce, then 4-entry LDS combine, one atomic per block
#pragma unroll
    for (int off = 32; off; off >>= 1) facc += __shfl_xor(facc, off);
    if (lane == 0) sdl4[wave] = (double)facc;
    __syncthreads();
    if (tid == 0) {
        const double C_SS = 1.0 / 8386560.0;   // n_s*(n_s-1)/2 == n_t*(n_t-1)/2
        const double C_ST = 2.0 / 16777216.0;  // 2/(n_s*n_t)
        double scale = (region == 2) ? -C_ST : C_SS;
        atomicAdd(&accum[2], scale * (sdl4[0] + sdl4[1] + sdl4[2] + sdl4[3]));
        __threadfence();
        unsigned int old = atomicAdd(cnt, 1u);
        if (old == NTILES - 1) {
            double v = atomicAdd(&accum[2], 0.0);  // device-scope coherent read
            out[0] = (float)v;
        }
    }
}

extern "C" void kernel_launch(void* const* d_in, const int* in_sizes, int n_in,
                              void* d_out, int out_size, void* d_ws, size_t ws_size,
                              hipStream_t stream) {
    const float* x    = (const float*)d_in[0];
    const float* imw  = (const float*)d_in[1];
    const int*   y    = (const int*)d_in[3];
    const int*   alph = (const int*)d_in[4];
    float* out = (float*)d_out;

    char* ws = (char*)d_ws;
    double*       accum   = (double*)ws;
    unsigned int* cnt     = (unsigned int*)(ws + 64);
    float*        invbw   = (float*)(ws + 128);
    float*        sq      = (float*)(ws + 4096);
    float*        wgt     = (float*)(ws + 36864);
    float*        colpart = (float*)(ws + 53248);
    unsigned short* xhi   = (unsigned short*)(ws + 577536);

    k_prep<<<NPREP, 256, 0, stream>>>(x, xhi, sq, colpart);
    k_bw<<<1, 256, 0, stream>>>(sq, colpart, imw, y, alph, wgt, invbw, accum, cnt);
    k_pairs<<<NTILES, 256, 0, stream>>>(xhi, sq, wgt, invbw, accum, cnt, out);
}